// Round 14
// baseline (1172.995 us; speedup 1.0000x reference)
//
#include <hip/hip_runtime.h>
#include <hip/hip_bf16.h>
#include <math.h>

#define B_ 32
#define L_ 128
#define LP 130      // padded L (zero row before/after each batch)
#define E_ 300
#define EP 384      // padded E (%128 for BK=128 x-region)
#define H_ 512
#define DOUT_ 5
#define NSTEP 5
#define G7 3584     // 7H
#define KGATES 1920 // 1536 (hl|h|hr from hpad) + 384 (x padded)
#define KFI 512     // h only (g handled via gfi per-batch bias)

typedef __hip_bfloat16 bf16;
using bf16x8 = __attribute__((ext_vector_type(8))) __bf16;
using f32x4 = __attribute__((ext_vector_type(4))) float;

__device__ __forceinline__ void gload16(const void* g, void* l) {
  __builtin_amdgcn_global_load_lds(
      (const __attribute__((address_space(1))) void*)g,
      (__attribute__((address_space(3))) void*)l, 16, 0, 0);
}

// ---------------- small helpers ----------------
__global__ void fill_zero(float* __restrict__ p, int n) {
  int i = blockIdx.x * blockDim.x + threadIdx.x;
  if (i < n) p[i] = 0.f;
}

__global__ void mask_lens_kernel(const int* __restrict__ lengths,
                                 float* __restrict__ maskf,
                                 float* __restrict__ invlens) {
  int i = blockIdx.x * blockDim.x + threadIdx.x;
  if (i < B_ * L_) {
    int b = i >> 7, l = i & 127;
    maskf[i] = (l < lengths[b]) ? 1.f : 0.f;
    if (l == 0) invlens[b] = 1.f / fmaxf((float)lengths[b], 1.f);
  }
}

__global__ void embed_bf16_kernel(const int* __restrict__ tokens,
                                  const float* __restrict__ embed,
                                  bf16* __restrict__ xb) {
  int i = blockIdx.x * blockDim.x + threadIdx.x;  // B*L*EP
  if (i >= B_ * L_ * EP) return;
  int e = i % EP, bl = i / EP;
  float v = (e < E_) ? embed[(size_t)tokens[bl] * E_ + e] : 0.f;
  xb[i] = __float2bfloat16(v);
}

__global__ void fill_pad2(bf16* __restrict__ hpad0, bf16* __restrict__ hpad1) {
  int i = blockIdx.x * blockDim.x + threadIdx.x;  // B*2*H
  if (i >= B_ * 2 * H_) return;
  int hh = i & (H_ - 1);
  int r = (i >> 9) & 1, b = i >> 10;
  size_t oi = ((size_t)(b * LP + r * (LP - 1))) * H_ + hh;
  hpad0[oi] = __float2bfloat16(0.f);
  hpad1[oi] = __float2bfloat16(0.f);
}

// transpose + cast: Wt[n][k] = W[k][n]; grid (Kregion/64, Ncols/64).
__global__ __launch_bounds__(256) void transpose_to_bf16(
    const float* __restrict__ W, bf16* __restrict__ Wt, int Kreal, int Ncols,
    int dstStride) {
  __shared__ float tile[64][65];
  const int k0 = blockIdx.x * 64, n0 = blockIdx.y * 64;
  const int t = threadIdx.x;
  const int nn = t & 63, kk0 = t >> 6;
#pragma unroll
  for (int p = 0; p < 16; ++p) {
    int kk = kk0 + p * 4;
    int gk = k0 + kk;
    tile[kk][nn] = (gk < Kreal) ? W[(size_t)gk * Ncols + n0 + nn] : 0.f;
  }
  __syncthreads();
#pragma unroll
  for (int p = 0; p < 2; ++p) {
    int r = (t >> 3) + p * 32;
    int kb = (t & 7) * 8;
    union { ushort h[8]; uint4 v; } u;
#pragma unroll
    for (int e = 0; e < 8; ++e) {
      bf16 b = __float2bfloat16(tile[kb + e][r]);
      u.h[e] = *(ushort*)&b;
    }
    *(uint4*)&Wt[(size_t)(n0 + r) * dstStride + k0 + kb] = u.v;
  }
}

// ---------------- init GEMM: 128x128, BK=64, tanh+mask -> hpad ---------------
__global__ __launch_bounds__(256) void gemm_mfma_init(
    const bf16* __restrict__ A, const bf16* __restrict__ Bt,
    const float* __restrict__ bias, const float* __restrict__ rowscale,
    bf16* __restrict__ Cout, int N, int KP) {
  __shared__ ushort As[128 * 64];
  __shared__ ushort Bs[128 * 64];
  const int tid = threadIdx.x;
  const int lane = tid & 63;
  const int w = tid >> 6;
  const int wr = w >> 1, wc = w & 1;
  const int nbx = gridDim.x;
  const int nwg = nbx * gridDim.y;
  int id = blockIdx.y * nbx + blockIdx.x;
  if ((nwg & 7) == 0) { int q = nwg >> 3; id = (id & 7) * q + (id >> 3); }
  const int bxi = id % nbx, byi = id / nbx;
  const int rowBase = byi * 128, colBase = bxi * 128;
  const int l15 = lane & 15, l4 = lane >> 4;
  f32x4 acc[4][4] = {};

  const bf16* bP[4];
  const bf16* aP[4];
#pragma unroll
  for (int i = 0; i < 4; ++i) {
    int c = tid + 256 * i;
    int r = c >> 3;
    int ql = (c & 7) ^ (r & 7);
    bP[i] = Bt + (size_t)(colBase + r) * KP + ql * 8;
    aP[i] = A + (size_t)(rowBase + r) * KP + ql * 8;
  }

  const int nIter = KP >> 6;
  for (int t = 0; t < nIter; ++t) {
    int k0 = t * 64;
#pragma unroll
    for (int i = 0; i < 4; ++i) {
      gload16(aP[i] + k0, &As[(tid + 256 * i) * 8]);
      gload16(bP[i] + k0, &Bs[(tid + 256 * i) * 8]);
    }
    __syncthreads();
#pragma unroll
    for (int kh = 0; kh < 2; ++kh) {
      bf16x8 aF[4], bF[4];
#pragma unroll
      for (int m = 0; m < 4; ++m) {
        int row = wr * 64 + m * 16 + l15;
        aF[m] = *(const bf16x8*)&As[row * 64 +
                                    (((kh << 2) + l4) ^ (l15 & 7)) * 8];
      }
#pragma unroll
      for (int n = 0; n < 4; ++n) {
        int row = wc * 64 + n * 16 + l15;
        bF[n] = *(const bf16x8*)&Bs[row * 64 +
                                    (((kh << 2) + l4) ^ (l15 & 7)) * 8];
      }
#pragma unroll
      for (int m = 0; m < 4; ++m)
#pragma unroll
        for (int n = 0; n < 4; ++n)
          acc[m][n] = __builtin_amdgcn_mfma_f32_16x16x32_bf16(
              aF[m], bF[n], acc[m][n], 0, 0, 0);
    }
    __syncthreads();
  }

#pragma unroll
  for (int m = 0; m < 4; ++m) {
#pragma unroll
    for (int n = 0; n < 4; ++n) {
      int col = colBase + wc * 64 + n * 16 + l15;
      float bv = bias[col];
#pragma unroll
      for (int j = 0; j < 4; ++j) {
        int row = rowBase + wr * 64 + m * 16 + l4 * 4 + j;
        float v = tanhf(acc[m][n][j] + bv) * rowscale[row];
        size_t oi = ((size_t)((row >> 7) * LP + (row & 127) + 1)) * H_ + col;
        Cout[oi] = __float2bfloat16(v);
      }
    }
  }
}

// ---------------- fused gates GEMM + cell update + h-mean (split-K) ---------
// BM=64 (half-batch), BN=112 (16 h x 7 gates), BK=128, K=1920 (15 steps).
// Split-K across waves: each wave computes the FULL 4x7 fragment grid on its
// own K=32 slice (chunk base w*4) -> 11 ds_reads : 28 MFMAs per step.
// Partials reduced via LDS (transposed sfi[112][68], f32x4 ops, 4 passes).
// grid (32, 64), XCD column-chunk decode: each XCD owns 4 bxi (Wgt slice
// L2-resident). B-row pointers apply gate-major -> h-major permutation.
__global__ __launch_bounds__(256) void gates_cell_kernel(
    const bf16* __restrict__ hpad_old, const bf16* __restrict__ xb,
    const bf16* __restrict__ Wgt, const float* __restrict__ bg,
    const float* __restrict__ gg, const int* __restrict__ lengths,
    const bf16* __restrict__ c_old, const float* __restrict__ cg_old,
    bf16* __restrict__ c_new, bf16* __restrict__ hpad_new,
    float* __restrict__ havg_part) {
  __shared__ __align__(16) char smem[(64 + 112) * 128 * 2];  // 45056 B
  ushort* As = (ushort*)smem;            // [64][128]  (K-loop)
  ushort* Bs = As + 64 * 128;            // [112][128] (K-loop)
  float* sfi = (float*)smem;             // [112][68]  (epilogue, transposed)
  float* red = sfi + 112 * 68;           // [16][16]

  const int tid = threadIdx.x;
  const int lane = tid & 63;
  const int w = tid >> 6;
  int worig = blockIdx.y * 32 + blockIdx.x;
  int id = (worig & 7) * 256 + (worig >> 3);  // nwg=2048, bijective
  const int bxi = id >> 6;   // 0..31 -> column block (XCD-local)
  const int byi = id & 63;   // 0..63 -> half-batch
  const int b = byi >> 1, lhalf = byi & 1;
  const int len = lengths[b];
  if (lhalf && len <= 64) return;
  const int l15 = lane & 15, l4 = lane >> 4;
  f32x4 acc[4][7] = {};

  const int hRowBase = b * LP + lhalf * 64;
  const int blBase = b * L_ + lhalf * 64;
  const bf16* aP[4];
  const bf16* xP[4];
  const bf16* bP[7];
  bool aOk[4];
#pragma unroll
  for (int i = 0; i < 4; ++i) {
    int c = tid + 256 * i;  // 0..1023
    int r = c >> 4;         // 0..63
    int ql = (c & 15) ^ (r & 7);
    aP[i] = hpad_old + (size_t)(hRowBase + r) * H_ + ql * 8;
    xP[i] = xb + (size_t)(blBase + r) * EP + ql * 8;
    aOk[i] = (lhalf * 64 + r) < len;  // rows >= len masked, never consumed
  }
#pragma unroll
  for (int i = 0; i < 7; ++i) {
    int c = tid + 256 * i;  // 0..1791
    int r = c >> 4;         // 0..111
    int ql = (c & 15) ^ (r & 7);
    int j = bxi * 112 + r;              // h-major col index
    int src = (j % 7) * 512 + (j / 7);  // natural gate-major Wg col
    bP[i] = Wgt + (size_t)src * KGATES + ql * 8;
  }

  const int kc = w * 4;  // wave's K-chunk base within BK=128

  auto step_ = [&](const bf16* const* ap, int ko, int kb) {
#pragma unroll
    for (int i = 0; i < 4; ++i)
      if (aOk[i]) gload16(ap[i] + ko, &As[(tid + 256 * i) * 8]);
#pragma unroll
    for (int i = 0; i < 7; ++i)
      gload16(bP[i] + kb, &Bs[(tid + 256 * i) * 8]);
    __syncthreads();
    bf16x8 aF[4], bF[7];
#pragma unroll
    for (int m = 0; m < 4; ++m) {
      int row = m * 16 + l15;
      aF[m] = *(const bf16x8*)&As[row * 128 + ((kc + l4) ^ (row & 7)) * 8];
    }
#pragma unroll
    for (int n = 0; n < 7; ++n) {
      int row = n * 16 + l15;
      bF[n] = *(const bf16x8*)&Bs[row * 128 + ((kc + l4) ^ (row & 7)) * 8];
    }
#pragma unroll
    for (int m = 0; m < 4; ++m)
#pragma unroll
      for (int n = 0; n < 7; ++n)
        acc[m][n] = __builtin_amdgcn_mfma_f32_16x16x32_bf16(aF[m], bF[n],
                                                            acc[m][n], 0, 0, 0);
    __syncthreads();
  };

  for (int t = 0; t < 12; ++t) step_(aP, t * 128, t * 128);
  for (int t = 12; t < 15; ++t) step_(xP, (t - 12) * 128, t * 128);

  // reduce 4 wave-partials into sfi (transposed: sfi[col][row], f32x4 rows)
#pragma unroll
  for (int ww = 0; ww < 4; ++ww) {
    if (w == ww) {
#pragma unroll
      for (int m = 0; m < 4; ++m)
#pragma unroll
        for (int n = 0; n < 7; ++n) {
          int col = n * 16 + l15;
          int row0 = m * 16 + l4 * 4;
          float* dst = &sfi[col * 68 + row0];
          if (ww == 0) {
            *(f32x4*)dst = acc[m][n];
          } else {
            f32x4 v = *(const f32x4*)dst;
            v += acc[m][n];
            *(f32x4*)dst = v;
          }
        }
    }
    __syncthreads();
  }

  // cell update: thread -> h_loc = tid&15, l-group = tid>>4 (4 l's each)
  const int hloc = tid & 15;
  const int lgrp = tid >> 4;
  const int hglob = bxi * 16 + hloc;
  float bv[7];
#pragma unroll
  for (int g = 0; g < 7; ++g)
    bv[g] = bg[g * 512 + hglob] + gg[(size_t)b * G7 + g * 512 + hglob];
  const float cgv = cg_old[b * H_ + hglob];
  float s = 0.f;
#pragma unroll
  for (int it = 0; it < 4; ++it) {
    int loc = lgrp + it * 16;        // 0..63
    int lglob = lhalf * 64 + loc;
    int bl = b * L_ + lglob;
    size_t coi = (size_t)bl * H_ + hglob;
    size_t hoi = ((size_t)(b * LP + lglob + 1)) * H_ + hglob;
    if (lglob >= len) {
      c_new[coi] = __float2bfloat16(0.f);
      hpad_new[hoi] = __float2bfloat16(0.f);
      continue;
    }
    float gl_[7];
#pragma unroll
    for (int g = 0; g < 7; ++g)
      gl_[g] = sfi[(hloc * 7 + g) * 68 + loc] + bv[g];
    float m = fmaxf(fmaxf(fmaxf(gl_[0], gl_[1]), fmaxf(gl_[2], gl_[3])),
                    gl_[4]);
    float ei = expf(gl_[0] - m), el = expf(gl_[1] - m), ef = expf(gl_[2] - m),
          er = expf(gl_[3] - m), es = expf(gl_[4] - m);
    float inv = 1.f / (ei + el + ef + er + es);
    float o = 1.f / (1.f + expf(-gl_[5]));
    float u = tanhf(gl_[6]);
    float cprev = (lglob >= 1) ? __bfloat162float(c_old[coi - H_]) : 0.f;
    float ccur = __bfloat162float(c_old[coi]);
    float cnext = (lglob < L_ - 1) ? __bfloat162float(c_old[coi + H_]) : 0.f;
    float cn = (el * cprev + ef * ccur + er * cnext + es * cgv + ei * u) * inv;
    float hn = o * tanhf(cn);
    c_new[coi] = __float2bfloat16(cn);
    hpad_new[hoi] = __float2bfloat16(hn);
    s += hn;
  }
  red[hloc * 16 + lgrp] = s;
  __syncthreads();
  if (tid < 16) {
    float v = 0.f;
#pragma unroll
    for (int k = 0; k < 16; ++k) v += red[tid * 16 + k];
    havg_part[(size_t)lhalf * B_ * H_ + (size_t)b * H_ + bxi * 16 + tid] = v;
  }
}

// ---------------- per-batch g-vector GEMMs: gg = g@Wg_g, gfi = g@Wfi_top ----
__global__ __launch_bounds__(256) void gvec_gemm(
    const float* __restrict__ g, const float* __restrict__ Wgg,
    const float* __restrict__ Wfi, float* __restrict__ gg,
    float* __restrict__ gfi) {
  __shared__ float vin[H_];
  __shared__ float red[4][64];
  const int b = blockIdx.y;
  for (int i = threadIdx.x; i < H_; i += 256) vin[i] = g[(size_t)b * H_ + i];
  __syncthreads();
  const int o = threadIdx.x & 63, kp = threadIdx.x >> 6;
  const bool isg = blockIdx.x < 56;
  const int n0 = isg ? blockIdx.x * 64 : (blockIdx.x - 56) * 64;
  const float* W = isg ? Wgg : Wfi;
  const int ldw = isg ? G7 : H_;
  float acc = 0.f;
#pragma unroll 4
  for (int k = kp * 128; k < kp * 128 + 128; ++k)
    acc = fmaf(vin[k], W[(size_t)k * ldw + n0 + o], acc);
  red[kp][o] = acc;
  __syncthreads();
  if (threadIdx.x < 64) {
    int t = threadIdx.x;
    float v = red[0][t] + red[1][t] + red[2][t] + red[3][t];
    if (isg) gg[(size_t)b * G7 + n0 + t] = v;
    else gfi[(size_t)b * H_ + n0 + t] = v;
  }
}

// ---------------- fg/og from (g, havg parts): grid (8, B, 2) ----------------
__global__ __launch_bounds__(256) void gnode_vec(
    const float* __restrict__ g, const float* __restrict__ havg_part,
    const float* __restrict__ invlens, const float* __restrict__ Wgf,
    const float* __restrict__ bgf, float* __restrict__ fg,
    const float* __restrict__ Wgo, const float* __restrict__ bgo,
    float* __restrict__ og) {
  const int z = blockIdx.z;
  const float* W = z ? Wgo : Wgf;
  const float* bias = z ? bgo : bgf;
  float* op = z ? og : fg;
  __shared__ float vin[1024];
  __shared__ float red[4][64];
  const int n0 = blockIdx.x * 64, b = blockIdx.y;
  const float il = invlens[b];
  for (int i = threadIdx.x; i < 1024; i += 256)
    vin[i] = (i < 512) ? g[(size_t)b * H_ + i]
                       : (havg_part[(size_t)b * H_ + (i - 512)] +
                          havg_part[(size_t)(B_ + b) * H_ + (i - 512)]) * il;
  __syncthreads();
  const int o = threadIdx.x & 63, kp = threadIdx.x >> 6;
  float acc = 0.f;
#pragma unroll 4
  for (int k = kp * 256; k < kp * 256 + 256; ++k)
    acc = fmaf(vin[k], W[(size_t)k * H_ + n0 + o], acc);
  red[kp][o] = acc;
  __syncthreads();
  if (threadIdx.x < 64) {
    int t = threadIdx.x;
    float v = red[0][t] + red[1][t] + red[2][t] + red[3][t] + bias[n0 + t];
    if (z) v = 1.f / (1.f + expf(-v));
    op[(size_t)b * H_ + n0 + t] = v;
  }
}

// ---------------- fused fi GEMM (K=512) + slot softmax, 64-col tiles --------
__global__ __launch_bounds__(256) void fi_slot_kernel(
    const bf16* __restrict__ hpad, const bf16* __restrict__ Wfit,
    const float* __restrict__ bfi, const float* __restrict__ gfi,
    const float* __restrict__ fg, const float* __restrict__ og,
    const bf16* __restrict__ c_new, const float* __restrict__ cg_old,
    const float* __restrict__ maskf, const int* __restrict__ lengths,
    float* __restrict__ cg_new, float* __restrict__ g_new) {
  __shared__ __align__(16) char smem[64 * 129 * 4 + 3072];  // 36096 B
  ushort* As = (ushort*)smem;              // [128*64] staging (dead later)
  ushort* Bs = As + 128 * 64;              // [64*64]
  float* sfi = (float*)smem;               // [64 cols][129] after K-loop
  float* part = sfi + 64 * 129;            // [4][3][64]

  const int tid = threadIdx.x;
  const int lane = tid & 63;
  const int w = tid >> 6;                  // wave -> rows w*32..w*32+31
  const int b = blockIdx.y;
  const int len = lengths[b];
  const bool wactive = len > w * 32;
  const int colBase = blockIdx.x * 64;
  const int l15 = lane & 15, l4 = lane >> 4;
  f32x4 acc[2][4] = {};

  const bf16* aP[4];
  bool aOk[4];
  const bf16* bP[2];
#pragma unroll
  for (int i = 0; i < 4; ++i) {
    int c = tid + 256 * i;
    int r = c >> 3;
    int ql = (c & 7) ^ (r & 7);
    aP[i] = hpad + ((size_t)(b * LP + r + 1)) * H_ + ql * 8;
    aOk[i] = r < len;
  }
#pragma unroll
  for (int i = 0; i < 2; ++i) {
    int c = tid + 256 * i;
    int r = c >> 3;
    int ql = (c & 7) ^ (r & 7);
    bP[i] = Wfit + (size_t)(colBase + r) * KFI + ql * 8;
  }

  for (int t = 0; t < 8; ++t) {
    int k0 = t * 64;
#pragma unroll
    for (int i = 0; i < 4; ++i)
      if (aOk[i]) gload16(aP[i] + k0, &As[(tid + 256 * i) * 8]);
#pragma unroll
    for (int i = 0; i < 2; ++i)
      gload16(bP[i] + k0, &Bs[(tid + 256 * i) * 8]);
    __syncthreads();
    if (wactive) {
#pragma unroll
      for (int kh = 0; kh < 2; ++kh) {
        bf16x8 aF[2], bF[4];
#pragma unroll
        for (int m = 0; m < 2; ++m) {
          int row = w * 32 + m * 16 + l15;
          aF[m] = *(const bf16x8*)&As[row * 64 +
                                      (((kh << 2) + l4) ^ (l15 & 7)) * 8];
        }
#pragma unroll
        for (int n = 0; n < 4; ++n) {
          int row = n * 16 + l15;
          bF[n] = *(const bf16x8*)&Bs[row * 64 +
                                      (((kh << 2) + l4) ^ (l15 & 7)) * 8];
        }
#pragma unroll
        for (int m = 0; m < 2; ++m)
#pragma unroll
          for (int n = 0; n < 4; ++n)
            acc[m][n] = __builtin_amdgcn_mfma_f32_16x16x32_bf16(
                aF[m], bF[n], acc[m][n], 0, 0, 0);
      }
    }
    __syncthreads();
  }

  // fi tile -> LDS (only active waves; inactive rows never read)
  if (wactive) {
#pragma unroll
    for (int m = 0; m < 2; ++m) {
#pragma unroll
      for (int n = 0; n < 4; ++n) {
        int hl_ = n * 16 + l15;
        float bv = bfi[colBase + hl_] + gfi[(size_t)b * H_ + colBase + hl_];
#pragma unroll
        for (int j = 0; j < 4; ++j) {
          int l = w * 32 + m * 16 + l4 * 4 + j;
          sfi[hl_ * 129 + l] = acc[m][n][j] + bv;
        }
      }
    }
  }
  __syncthreads();

  // online softmax over slots: 4 threads per column, 32 l each
  {
    int h = tid & 63, q = tid >> 6;
    int hcol = colBase + h;
    const float* mp = maskf + b * L_;
    float m = -3.0e38f, s = 0.f, tv = 0.f;
    if (len > q * 32) {
      for (int l = q * 32; l < q * 32 + 32; ++l) {
        if (mp[l] > 0.f) {
          float xv = sfi[h * 129 + l];
          float vv =
              __bfloat162float(c_new[((size_t)(b * L_ + l)) * H_ + hcol]);
          float m2 = fmaxf(m, xv);
          float sc = expf(m - m2);
          float e = expf(xv - m2);
          s = s * sc + e;
          tv = tv * sc + e * vv;
          m = m2;
        }
      }
    }
    part[q * 192 + h] = m;
    part[q * 192 + 64 + h] = s;
    part[q * 192 + 128 + h] = tv;
  }
  __syncthreads();
  if (tid < 64) {
    int hcol = colBase + tid;
    int i0 = b * H_ + hcol;
    float mm = part[tid], s0 = part[64 + tid], t0 = part[128 + tid];
#pragma unroll
    for (int k = 1; k < 4; ++k) {
      float mk = part[k * 192 + tid];
      float m2 = fmaxf(mm, mk);
      float e1 = expf(mm - m2), e2 = expf(mk - m2);
      s0 = s0 * e1 + part[k * 192 + 64 + tid] * e2;
      t0 = t0 * e1 + part[k * 192 + 128 + tid] * e2;
      mm = m2;
    }
    float f = fg[i0];
    float m2 = fmaxf(mm, f);
    float ea = expf(mm - m2), eb = expf(f - m2);
    s0 = s0 * ea + eb;
    t0 = t0 * ea + cg_old[i0] * eb;
    float cgn = t0 / s0;
    float gn = og[i0] * tanhf(cgn);
    cg_new[i0] = cgn;
    g_new[i0] = gn;
  }
}

// deterministic parallel mean over L from bf16 hpad (init only)
__global__ __launch_bounds__(256) void reduce_mean_v2(
    const bf16* __restrict__ hpad, const float* __restrict__ invlens,
    float* __restrict__ outf) {
  __shared__ float sm[4][64];
  int b = blockIdx.y, h0 = blockIdx.x * 64;
  int lg = threadIdx.x >> 6, hh = threadIdx.x & 63;
  float s = 0.f;
  for (int l = lg * 32; l < lg * 32 + 32; ++l)
    s += __bfloat162float(hpad[((size_t)(b * LP + l + 1)) * H_ + h0 + hh]);
  sm[lg][hh] = s;
  __syncthreads();
  if (threadIdx.x < 64) {
    int t = threadIdx.x;
    outf[b * H_ + h0 + t] =
        (sm[0][t] + sm[1][t] + sm[2][t] + sm[3][t]) * invlens[b];
  }
}

// ---------------- fused final head -------------------------------------------
__global__ __launch_bounds__(256) void final_head_kernel(
    const float* __restrict__ g, const float* __restrict__ W1,
    const float* __restrict__ b1, const float* __restrict__ W2,
    const float* __restrict__ b2, float* __restrict__ out) {
  __shared__ float gv[H_];
  __shared__ float t1s[2 * H_];
  __shared__ float red[256][6];
  const int b = blockIdx.x;
  const int tid = threadIdx.x;
  for (int i = tid; i < H_; i += 256) gv[i] = g[b * H_ + i];
  __syncthreads();
  float accp[4];
#pragma unroll
  for (int p = 0; p < 4; ++p) accp[p] = b1[tid + p * 256];
  for (int k = 0; k < H_; ++k) {
    float gk = gv[k];
#pragma unroll
    for (int p = 0; p < 4; ++p)
      accp[p] = fmaf(gk, W1[(size_t)k * (2 * H_) + tid + p * 256], accp[p]);
  }
#pragma unroll
  for (int p = 0; p < 4; ++p) t1s[tid + p * 256] = tanhf(accp[p]);
  __syncthreads();
  float pd[DOUT_] = {0.f, 0.f, 0.f, 0.f, 0.f};
#pragma unroll
  for (int p = 0; p < 4; ++p) {
    int j = tid + p * 256;
    float tv = t1s[j];
#pragma unroll
    for (int d = 0; d < DOUT_; ++d)
      pd[d] = fmaf(tv, W2[(size_t)j * DOUT_ + d], pd[d]);
  }
#pragma unroll
  for (int d = 0; d < DOUT_; ++d) red[tid][d] = pd[d];
  __syncthreads();
  for (int stride = 128; stride >= 1; stride >>= 1) {
    if (tid < stride) {
#pragma unroll
      for (int d = 0; d < DOUT_; ++d) red[tid][d] += red[tid + stride][d];
    }
    __syncthreads();
  }
  if (tid == 0) {
    float lg[DOUT_];
#pragma unroll
    for (int d = 0; d < DOUT_; ++d) lg[d] = red[0][d] + b2[d];
    float m = lg[0];
#pragma unroll
    for (int d = 1; d < DOUT_; ++d) m = fmaxf(m, lg[d]);
    float s = 0.f;
#pragma unroll
    for (int d = 0; d < DOUT_; ++d) s += expf(lg[d] - m);
    float ls = logf(s);
#pragma unroll
    for (int d = 0; d < DOUT_; ++d) out[b * DOUT_ + d] = lg[d] - m - ls;
  }
}

// ---------------- host ----------------
extern "C" void kernel_launch(void* const* d_in, const int* in_sizes, int n_in,
                              void* d_out, int out_size, void* d_ws,
                              size_t ws_size, hipStream_t stream) {
  (void)in_sizes; (void)n_in; (void)out_size; (void)ws_size;
  const int* tokens = (const int*)d_in[0];
  const int* lengths = (const int*)d_in[1];
  const float* embed = (const float*)d_in[2];
  const float* W0 = (const float*)d_in[3];
  const float* b0 = (const float*)d_in[4];
  const float* Wg = (const float*)d_in[5];
  const float* bg = (const float*)d_in[6];
  const float* Wgf = (const float*)d_in[7];
  const float* bgf = (const float*)d_in[8];
  const float* Wfi = (const float*)d_in[9];
  const float* bfi = (const float*)d_in[10];
  const float* Wgo = (const float*)d_in[11];
  const float* bgo = (const float*)d_in[12];
  const float* W1 = (const float*)d_in[13];
  const float* b1 = (const float*)d_in[14];
  const float* W2 = (const float*)d_in[15];
  const float* b2 = (const float*)d_in[16];
  float* out = (float*)d_out;

  float* ws = (float*)d_ws;
  size_t off = 0;
  auto alloc = [&](size_t nf) {
    float* p = ws + off;
    off += (nf + 7) & ~(size_t)7;
    return p;
  };
  bf16* xb = (bf16*)alloc((size_t)B_ * L_ * EP / 2);       // [4096][384]
  float* maskf = alloc(B_ * L_);
  float* invlens = alloc(B_);
  bf16* hpad0 = (bf16*)alloc((size_t)B_ * LP * H_ / 2);    // [32][130][512]
  bf16* hpad1 = (bf16*)alloc((size_t)B_ * LP * H_ / 2);
  bf16* cb0 = (bf16*)alloc((size_t)B_ * L_ * H_ / 2);      // bf16 c
  bf16* cb1 = (bf16*)alloc((size_t)B_ * L_ * H_ / 2);
  float* g = alloc(B_ * H_);
  float* cgb0 = alloc(B_ * H_);
  float* cgb1 = alloc(B_ * H_);
  float* havg_part = alloc((size_t)2 * B_ * H_);           // [2][32][512]
  float* fg = alloc(B_ * H_);
  float* og = alloc(B_ * H_);
  float* gg = alloc((size_t)B_ * G7);                      // [32][3584]
  float* gfi = alloc(B_ * H_);                             // [32][512]
  bf16* Wgt = (bf16*)alloc((size_t)G7 * KGATES / 2);       // [3584][1920]
  bf16* W0t = (bf16*)alloc((size_t)H_ * EP / 2);           // [512][384]
  bf16* Wfit = (bf16*)alloc((size_t)H_ * KFI / 2);         // [512][512]

  // ---- init ----
  mask_lens_kernel<<<(B_ * L_ + 255) / 256, 256, 0, stream>>>(lengths, maskf,
                                                              invlens);
  embed_bf16_kernel<<<(B_ * L_ * EP + 255) / 256, 256, 0, stream>>>(tokens,
                                                                    embed, xb);
  // Wgt cols: [0,1536)=Wg rows[0,1536) (hl|h|hr); [1536,1920)=rows[1536,1836)
  // (x region, 300 real zero-padded to 384). g rows handled by gvec_gemm.
  transpose_to_bf16<<<dim3(24, G7 / 64), 256, 0, stream>>>(Wg, Wgt, 1536, G7,
                                                           KGATES);
  transpose_to_bf16<<<dim3(6, G7 / 64), 256, 0, stream>>>(
      Wg + (size_t)1536 * G7, Wgt + 1536, 300, G7, KGATES);
  transpose_to_bf16<<<dim3(6, H_ / 64), 256, 0, stream>>>(W0, W0t, 300, H_, EP);
  transpose_to_bf16<<<dim3(8, H_ / 64), 256, 0, stream>>>(
      Wfi + (size_t)H_ * H_, Wfit, H_, H_, KFI);  // bottom 512 rows (h part)
  fill_pad2<<<(B_ * 2 * H_ + 255) / 256, 256, 0, stream>>>(hpad0, hpad1);
  // h0 = tanh(xb @ W0 + b0) * mask -> hpad0
  gemm_mfma_init<<<dim3(H_ / 128, (B_ * L_) / 128), 256, 0, stream>>>(
      xb, W0t, b0, maskf, hpad0, H_, EP);
  reduce_mean_v2<<<dim3(8, B_), 256, 0, stream>>>(hpad0, invlens, g);
  fill_zero<<<(B_ * L_ * H_ / 2 + 255) / 256, 256, 0, stream>>>(
      (float*)cb0, B_ * L_ * H_ / 2);
  fill_zero<<<(B_ * H_ + 255) / 256, 256, 0, stream>>>(cgb0, B_ * H_);
  fill_zero<<<(B_ * H_ + 255) / 256, 256, 0, stream>>>(havg_part + B_ * H_,
                                                       B_ * H_);

  bf16* cb[2] = {cb0, cb1};
  bf16* hp[2] = {hpad0, hpad1};
  float* cgb[2] = {cgb0, cgb1};
  int cur = 0;
  for (int step = 0; step < NSTEP; ++step) {
    int nxt = cur ^ 1;
    // per-batch g contributions (gg for gates, gfi for fi)
    gvec_gemm<<<dim3(64, B_), 256, 0, stream>>>(g, Wg + (size_t)1836 * G7,
                                                Wfi, gg, gfi);
    // gates GEMM + cell update + h-mean, fused (split-K)
    gates_cell_kernel<<<dim3(32, 64), 256, 0, stream>>>(
        hp[cur], xb, Wgt, bg, gg, lengths, cb[cur], cgb[cur], cb[nxt],
        hp[nxt], havg_part);
    gnode_vec<<<dim3(8, B_, 2), 256, 0, stream>>>(
        g, havg_part, invlens, Wgf, bgf, fg, Wgo, bgo, og);
    fi_slot_kernel<<<dim3(8, B_), 256, 0, stream>>>(
        hp[nxt], Wfit, bfi, gfi, fg, og, cb[nxt], cgb[cur], maskf, lengths,
        cgb[nxt], g);
    cur = nxt;
  }
  final_head_kernel<<<B_, 256, 0, stream>>>(g, W1, b1, W2, b2, out);
}

// Round 15
// 676.464 us; speedup vs baseline: 1.7340x; 1.7340x over previous
//
#include <hip/hip_runtime.h>
#include <hip/hip_bf16.h>
#include <math.h>

#define B_ 32
#define L_ 128
#define LP 130      // padded L (zero row before/after each batch)
#define E_ 300
#define EP 320      // padded E (%64)
#define H_ 512
#define DOUT_ 5
#define NSTEP 5
#define G7 3584     // 7H
#define KGATES 1856 // 1536 (hl|h|hr from hpad) + 320 (x padded)
#define KFI 512     // h only (g handled via gfi per-batch bias)

typedef __hip_bfloat16 bf16;
using bf16x8 = __attribute__((ext_vector_type(8))) __bf16;
using f32x4 = __attribute__((ext_vector_type(4))) float;

__device__ __forceinline__ void gload16(const void* g, void* l) {
  __builtin_amdgcn_global_load_lds(
      (const __attribute__((address_space(1))) void*)g,
      (__attribute__((address_space(3))) void*)l, 16, 0, 0);
}

// ---------------- small helpers ----------------
__global__ void fill_zero(float* __restrict__ p, int n) {
  int i = blockIdx.x * blockDim.x + threadIdx.x;
  if (i < n) p[i] = 0.f;
}

__global__ void mask_lens_kernel(const int* __restrict__ lengths,
                                 float* __restrict__ maskf,
                                 float* __restrict__ invlens) {
  int i = blockIdx.x * blockDim.x + threadIdx.x;
  if (i < B_ * L_) {
    int b = i >> 7, l = i & 127;
    maskf[i] = (l < lengths[b]) ? 1.f : 0.f;
    if (l == 0) invlens[b] = 1.f / fmaxf((float)lengths[b], 1.f);
  }
}

__global__ void embed_bf16_kernel(const int* __restrict__ tokens,
                                  const float* __restrict__ embed,
                                  bf16* __restrict__ xb) {
  int i = blockIdx.x * blockDim.x + threadIdx.x;  // B*L*EP
  if (i >= B_ * L_ * EP) return;
  int e = i % EP, bl = i / EP;
  float v = (e < E_) ? embed[(size_t)tokens[bl] * E_ + e] : 0.f;
  xb[i] = __float2bfloat16(v);
}

__global__ void fill_pad2(bf16* __restrict__ hpad0, bf16* __restrict__ hpad1) {
  int i = blockIdx.x * blockDim.x + threadIdx.x;  // B*2*H
  if (i >= B_ * 2 * H_) return;
  int hh = i & (H_ - 1);
  int r = (i >> 9) & 1, b = i >> 10;
  size_t oi = ((size_t)(b * LP + r * (LP - 1))) * H_ + hh;
  hpad0[oi] = __float2bfloat16(0.f);
  hpad1[oi] = __float2bfloat16(0.f);
}

// transpose + cast: Wt[n][k] = W[k][n]; grid (Kregion/64, Ncols/64).
__global__ __launch_bounds__(256) void transpose_to_bf16(
    const float* __restrict__ W, bf16* __restrict__ Wt, int Kreal, int Ncols,
    int dstStride) {
  __shared__ float tile[64][65];
  const int k0 = blockIdx.x * 64, n0 = blockIdx.y * 64;
  const int t = threadIdx.x;
  const int nn = t & 63, kk0 = t >> 6;
#pragma unroll
  for (int p = 0; p < 16; ++p) {
    int kk = kk0 + p * 4;
    int gk = k0 + kk;
    tile[kk][nn] = (gk < Kreal) ? W[(size_t)gk * Ncols + n0 + nn] : 0.f;
  }
  __syncthreads();
#pragma unroll
  for (int p = 0; p < 2; ++p) {
    int r = (t >> 3) + p * 32;
    int kb = (t & 7) * 8;
    union { ushort h[8]; uint4 v; } u;
#pragma unroll
    for (int e = 0; e < 8; ++e) {
      bf16 b = __float2bfloat16(tile[kb + e][r]);
      u.h[e] = *(ushort*)&b;
    }
    *(uint4*)&Wt[(size_t)(n0 + r) * dstStride + k0 + kb] = u.v;
  }
}

// ---------------- init GEMM: 128x128, BK=64, tanh+mask -> hpad ---------------
__global__ __launch_bounds__(256) void gemm_mfma_init(
    const bf16* __restrict__ A, const bf16* __restrict__ Bt,
    const float* __restrict__ bias, const float* __restrict__ rowscale,
    bf16* __restrict__ Cout, int N, int KP) {
  __shared__ ushort As[128 * 64];
  __shared__ ushort Bs[128 * 64];
  const int tid = threadIdx.x;
  const int lane = tid & 63;
  const int w = tid >> 6;
  const int wr = w >> 1, wc = w & 1;
  const int nbx = gridDim.x;
  const int nwg = nbx * gridDim.y;
  int id = blockIdx.y * nbx + blockIdx.x;
  if ((nwg & 7) == 0) { int q = nwg >> 3; id = (id & 7) * q + (id >> 3); }
  const int bxi = id % nbx, byi = id / nbx;
  const int rowBase = byi * 128, colBase = bxi * 128;
  const int l15 = lane & 15, l4 = lane >> 4;
  f32x4 acc[4][4] = {};

  const bf16* bP[4];
  const bf16* aP[4];
#pragma unroll
  for (int i = 0; i < 4; ++i) {
    int c = tid + 256 * i;
    int r = c >> 3;
    int ql = (c & 7) ^ (r & 7);
    bP[i] = Bt + (size_t)(colBase + r) * KP + ql * 8;
    aP[i] = A + (size_t)(rowBase + r) * KP + ql * 8;
  }

  const int nIter = KP >> 6;
  for (int t = 0; t < nIter; ++t) {
    int k0 = t * 64;
#pragma unroll
    for (int i = 0; i < 4; ++i) {
      gload16(aP[i] + k0, &As[(tid + 256 * i) * 8]);
      gload16(bP[i] + k0, &Bs[(tid + 256 * i) * 8]);
    }
    __syncthreads();
#pragma unroll
    for (int kh = 0; kh < 2; ++kh) {
      bf16x8 aF[4], bF[4];
#pragma unroll
      for (int m = 0; m < 4; ++m) {
        int row = wr * 64 + m * 16 + l15;
        aF[m] = *(const bf16x8*)&As[row * 64 +
                                    (((kh << 2) + l4) ^ (l15 & 7)) * 8];
      }
#pragma unroll
      for (int n = 0; n < 4; ++n) {
        int row = wc * 64 + n * 16 + l15;
        bF[n] = *(const bf16x8*)&Bs[row * 64 +
                                    (((kh << 2) + l4) ^ (l15 & 7)) * 8];
      }
#pragma unroll
      for (int m = 0; m < 4; ++m)
#pragma unroll
        for (int n = 0; n < 4; ++n)
          acc[m][n] = __builtin_amdgcn_mfma_f32_16x16x32_bf16(
              aF[m], bF[n], acc[m][n], 0, 0, 0);
    }
    __syncthreads();
  }

#pragma unroll
  for (int m = 0; m < 4; ++m) {
#pragma unroll
    for (int n = 0; n < 4; ++n) {
      int col = colBase + wc * 64 + n * 16 + l15;
      float bv = bias[col];
#pragma unroll
      for (int j = 0; j < 4; ++j) {
        int row = rowBase + wr * 64 + m * 16 + l4 * 4 + j;
        float v = tanhf(acc[m][n][j] + bv) * rowscale[row];
        size_t oi = ((size_t)((row >> 7) * LP + (row & 127) + 1)) * H_ + col;
        Cout[oi] = __float2bfloat16(v);
      }
    }
  }
}

// ---------------- fused gates GEMM + cell update + h-mean -------------------
// BM=128 (full batch), BN=112 (16 h x 7 gates), BK=64, K=1856 (29 steps).
// 4 waves x 32 rows each: per kh 2 A-reads + 7 B-reads for 14 MFMAs
// (read:MFMA = 0.64 vs 1.14 at BM=64). Wave-level length skip: wave w idles
// (barriers only) when w*32 >= len. Same read swizzle as the proven round-13
// kernel. Epilogue in two 64-row passes so sfi stays [112][68] f32.
// grid (32, 32), XCD column-chunk decode: each XCD owns 4 bxi (Wgt slice
// 1.66 MB, L2-resident). B-row pointers apply gate-major -> h-major perm.
__global__ __launch_bounds__(256) void gates_cell_kernel(
    const bf16* __restrict__ hpad_old, const bf16* __restrict__ xb,
    const bf16* __restrict__ Wgt, const float* __restrict__ bg,
    const float* __restrict__ gg, const int* __restrict__ lengths,
    const bf16* __restrict__ c_old, const float* __restrict__ cg_old,
    bf16* __restrict__ c_new, bf16* __restrict__ hpad_new,
    float* __restrict__ havg_part) {
  __shared__ __align__(16) char smem[31488];  // staging 30720 / epi 31488
  ushort* As = (ushort*)smem;            // [128][64] (K-loop)
  ushort* Bs = As + 128 * 64;            // [112][64] (K-loop)
  float* sfi = (float*)smem;             // [112][68] transposed (epilogue)
  float* red = sfi + 112 * 68;           // [16][16]

  const int tid = threadIdx.x;
  const int lane = tid & 63;
  const int w = tid >> 6;
  int worig = blockIdx.y * 32 + blockIdx.x;
  int id = (worig & 7) * 128 + (worig >> 3);  // nwg=1024, bijective
  const int bxi = id >> 5;   // 0..31 -> column block (XCD-local)
  const int b = id & 31;     // batch
  const int len = lengths[b];
  const bool wok = (w * 32) < len;  // wave's rows all masked if false
  const int l15 = lane & 15, l4 = lane >> 4;
  f32x4 acc[2][7] = {};

  const int hRowBase = b * LP;
  const int blBase = b * L_;
  const bf16* aP[4];
  const bf16* xP[4];
  const bf16* bP[4];
  bool aOk[4];
#pragma unroll
  for (int i = 0; i < 4; ++i) {
    int c = tid + 256 * i;  // 0..1023
    int r = c >> 3;         // 0..127
    int ql = (c & 7) ^ (r & 7);
    aP[i] = hpad_old + (size_t)(hRowBase + r) * H_ + ql * 8;
    xP[i] = xb + (size_t)(blBase + r) * EP + ql * 8;
    aOk[i] = r < len;  // rows >= len masked, never consumed
  }
#pragma unroll
  for (int i = 0; i < 4; ++i) {
    int c = tid + 256 * i;             // 0..1023 (only <896 used)
    int r = (c < 896) ? (c >> 3) : 0;  // 0..111
    int ql = (c & 7) ^ (r & 7);
    int j = bxi * 112 + r;              // h-major col index
    int src = (j % 7) * 512 + (j / 7);  // natural gate-major Wg col
    bP[i] = Wgt + (size_t)src * KGATES + ql * 8;
  }

  auto step_ = [&](const bf16* const* ap, int ko, int kb) {
#pragma unroll
    for (int i = 0; i < 4; ++i)
      if (aOk[i]) gload16(ap[i] + ko, &As[(tid + 256 * i) * 8]);
#pragma unroll
    for (int i = 0; i < 3; ++i)
      gload16(bP[i] + kb, &Bs[(tid + 256 * i) * 8]);
    if (tid < 128) gload16(bP[3] + kb, &Bs[(tid + 768) * 8]);
    __syncthreads();
    if (wok) {
#pragma unroll
      for (int kh = 0; kh < 2; ++kh) {
        bf16x8 aF[2], bF[7];
#pragma unroll
        for (int m = 0; m < 2; ++m) {
          int row = w * 32 + m * 16 + l15;
          aF[m] = *(const bf16x8*)&As[row * 64 +
                                      (((kh << 2) + l4) ^ (l15 & 7)) * 8];
        }
#pragma unroll
        for (int n = 0; n < 7; ++n) {
          int row = n * 16 + l15;
          bF[n] = *(const bf16x8*)&Bs[row * 64 +
                                      (((kh << 2) + l4) ^ (l15 & 7)) * 8];
        }
#pragma unroll
        for (int m = 0; m < 2; ++m)
#pragma unroll
          for (int n = 0; n < 7; ++n)
            acc[m][n] = __builtin_amdgcn_mfma_f32_16x16x32_bf16(
                aF[m], bF[n], acc[m][n], 0, 0, 0);
      }
    }
    __syncthreads();
  };

  for (int t = 0; t < 24; ++t) step_(aP, t * 64, t * 64);
  for (int t = 24; t < 29; ++t) step_(xP, (t - 24) * 64, t * 64);

  // epilogue: two 64-row passes (waves 2p,2p+1 own pass p's rows)
  const int hloc = tid & 15;
  const int lgrp = tid >> 4;
  const int hglob = bxi * 16 + hloc;
  float bv[7];
#pragma unroll
  for (int g = 0; g < 7; ++g)
    bv[g] = bg[g * 512 + hglob] + gg[(size_t)b * G7 + g * 512 + hglob];
  const float cgv = cg_old[b * H_ + hglob];
  float s = 0.f;
#pragma unroll
  for (int p = 0; p < 2; ++p) {
    if ((w >> 1) == p && wok) {
      const int wloc = w & 1;
#pragma unroll
      for (int m = 0; m < 2; ++m)
#pragma unroll
        for (int n = 0; n < 7; ++n) {
          int col = n * 16 + l15;
          int row0 = wloc * 32 + m * 16 + l4 * 4;
          *(f32x4*)&sfi[col * 68 + row0] = acc[m][n];
        }
    }
    __syncthreads();
#pragma unroll
    for (int it = 0; it < 4; ++it) {
      int loc = lgrp + it * 16;        // 0..63
      int lglob = p * 64 + loc;
      int bl = b * L_ + lglob;
      size_t coi = (size_t)bl * H_ + hglob;
      size_t hoi = ((size_t)(b * LP + lglob + 1)) * H_ + hglob;
      if (lglob >= len) {
        c_new[coi] = __float2bfloat16(0.f);
        hpad_new[hoi] = __float2bfloat16(0.f);
        continue;
      }
      float gl_[7];
#pragma unroll
      for (int g = 0; g < 7; ++g)
        gl_[g] = sfi[(hloc * 7 + g) * 68 + loc] + bv[g];
      float m = fmaxf(fmaxf(fmaxf(gl_[0], gl_[1]), fmaxf(gl_[2], gl_[3])),
                      gl_[4]);
      float ei = expf(gl_[0] - m), el = expf(gl_[1] - m),
            ef = expf(gl_[2] - m), er = expf(gl_[3] - m),
            es = expf(gl_[4] - m);
      float inv = 1.f / (ei + el + ef + er + es);
      float o = 1.f / (1.f + expf(-gl_[5]));
      float u = tanhf(gl_[6]);
      float cprev = (lglob >= 1) ? __bfloat162float(c_old[coi - H_]) : 0.f;
      float ccur = __bfloat162float(c_old[coi]);
      float cnext = (lglob < L_ - 1) ? __bfloat162float(c_old[coi + H_]) : 0.f;
      float cn =
          (el * cprev + ef * ccur + er * cnext + es * cgv + ei * u) * inv;
      float hn = o * tanhf(cn);
      c_new[coi] = __float2bfloat16(cn);
      hpad_new[hoi] = __float2bfloat16(hn);
      s += hn;
    }
    __syncthreads();  // sfi reads done before next pass overwrites
  }
  red[hloc * 16 + lgrp] = s;
  __syncthreads();
  if (tid < 16) {
    float v = 0.f;
#pragma unroll
    for (int k = 0; k < 16; ++k) v += red[tid * 16 + k];
    havg_part[(size_t)b * H_ + bxi * 16 + tid] = v;  // slot 0; slot 1 zeroed
  }
}

// ---------------- per-batch g-vector GEMMs: gg = g@Wg_g, gfi = g@Wfi_top ----
__global__ __launch_bounds__(256) void gvec_gemm(
    const float* __restrict__ g, const float* __restrict__ Wgg,
    const float* __restrict__ Wfi, float* __restrict__ gg,
    float* __restrict__ gfi) {
  __shared__ float vin[H_];
  __shared__ float red[4][64];
  const int b = blockIdx.y;
  for (int i = threadIdx.x; i < H_; i += 256) vin[i] = g[(size_t)b * H_ + i];
  __syncthreads();
  const int o = threadIdx.x & 63, kp = threadIdx.x >> 6;
  const bool isg = blockIdx.x < 56;
  const int n0 = isg ? blockIdx.x * 64 : (blockIdx.x - 56) * 64;
  const float* W = isg ? Wgg : Wfi;
  const int ldw = isg ? G7 : H_;
  float acc = 0.f;
#pragma unroll 4
  for (int k = kp * 128; k < kp * 128 + 128; ++k)
    acc = fmaf(vin[k], W[(size_t)k * ldw + n0 + o], acc);
  red[kp][o] = acc;
  __syncthreads();
  if (threadIdx.x < 64) {
    int t = threadIdx.x;
    float v = red[0][t] + red[1][t] + red[2][t] + red[3][t];
    if (isg) gg[(size_t)b * G7 + n0 + t] = v;
    else gfi[(size_t)b * H_ + n0 + t] = v;
  }
}

// ---------------- fg/og from (g, havg parts): grid (8, B, 2) ----------------
__global__ __launch_bounds__(256) void gnode_vec(
    const float* __restrict__ g, const float* __restrict__ havg_part,
    const float* __restrict__ invlens, const float* __restrict__ Wgf,
    const float* __restrict__ bgf, float* __restrict__ fg,
    const float* __restrict__ Wgo, const float* __restrict__ bgo,
    float* __restrict__ og) {
  const int z = blockIdx.z;
  const float* W = z ? Wgo : Wgf;
  const float* bias = z ? bgo : bgf;
  float* op = z ? og : fg;
  __shared__ float vin[1024];
  __shared__ float red[4][64];
  const int n0 = blockIdx.x * 64, b = blockIdx.y;
  const float il = invlens[b];
  for (int i = threadIdx.x; i < 1024; i += 256)
    vin[i] = (i < 512) ? g[(size_t)b * H_ + i]
                       : (havg_part[(size_t)b * H_ + (i - 512)] +
                          havg_part[(size_t)(B_ + b) * H_ + (i - 512)]) * il;
  __syncthreads();
  const int o = threadIdx.x & 63, kp = threadIdx.x >> 6;
  float acc = 0.f;
#pragma unroll 4
  for (int k = kp * 256; k < kp * 256 + 256; ++k)
    acc = fmaf(vin[k], W[(size_t)k * H_ + n0 + o], acc);
  red[kp][o] = acc;
  __syncthreads();
  if (threadIdx.x < 64) {
    int t = threadIdx.x;
    float v = red[0][t] + red[1][t] + red[2][t] + red[3][t] + bias[n0 + t];
    if (z) v = 1.f / (1.f + expf(-v));
    op[(size_t)b * H_ + n0 + t] = v;
  }
}

// ---------------- fused fi GEMM (K=512) + slot softmax, 64-col tiles --------
__global__ __launch_bounds__(256) void fi_slot_kernel(
    const bf16* __restrict__ hpad, const bf16* __restrict__ Wfit,
    const float* __restrict__ bfi, const float* __restrict__ gfi,
    const float* __restrict__ fg, const float* __restrict__ og,
    const bf16* __restrict__ c_new, const float* __restrict__ cg_old,
    const float* __restrict__ maskf, const int* __restrict__ lengths,
    float* __restrict__ cg_new, float* __restrict__ g_new) {
  __shared__ __align__(16) char smem[64 * 129 * 4 + 3072];  // 36096 B
  ushort* As = (ushort*)smem;              // [128*64] staging (dead later)
  ushort* Bs = As + 128 * 64;              // [64*64]
  float* sfi = (float*)smem;               // [64 cols][129] after K-loop
  float* part = sfi + 64 * 129;            // [4][3][64]

  const int tid = threadIdx.x;
  const int lane = tid & 63;
  const int w = tid >> 6;                  // wave -> rows w*32..w*32+31
  const int b = blockIdx.y;
  const int len = lengths[b];
  const bool wactive = len > w * 32;
  const int colBase = blockIdx.x * 64;
  const int l15 = lane & 15, l4 = lane >> 4;
  f32x4 acc[2][4] = {};

  const bf16* aP[4];
  bool aOk[4];
  const bf16* bP[2];
#pragma unroll
  for (int i = 0; i < 4; ++i) {
    int c = tid + 256 * i;
    int r = c >> 3;
    int ql = (c & 7) ^ (r & 7);
    aP[i] = hpad + ((size_t)(b * LP + r + 1)) * H_ + ql * 8;
    aOk[i] = r < len;
  }
#pragma unroll
  for (int i = 0; i < 2; ++i) {
    int c = tid + 256 * i;
    int r = c >> 3;
    int ql = (c & 7) ^ (r & 7);
    bP[i] = Wfit + (size_t)(colBase + r) * KFI + ql * 8;
  }

  for (int t = 0; t < 8; ++t) {
    int k0 = t * 64;
#pragma unroll
    for (int i = 0; i < 4; ++i)
      if (aOk[i]) gload16(aP[i] + k0, &As[(tid + 256 * i) * 8]);
#pragma unroll
    for (int i = 0; i < 2; ++i)
      gload16(bP[i] + k0, &Bs[(tid + 256 * i) * 8]);
    __syncthreads();
    if (wactive) {
#pragma unroll
      for (int kh = 0; kh < 2; ++kh) {
        bf16x8 aF[2], bF[4];
#pragma unroll
        for (int m = 0; m < 2; ++m) {
          int row = w * 32 + m * 16 + l15;
          aF[m] = *(const bf16x8*)&As[row * 64 +
                                      (((kh << 2) + l4) ^ (l15 & 7)) * 8];
        }
#pragma unroll
        for (int n = 0; n < 4; ++n) {
          int row = n * 16 + l15;
          bF[n] = *(const bf16x8*)&Bs[row * 64 +
                                      (((kh << 2) + l4) ^ (l15 & 7)) * 8];
        }
#pragma unroll
        for (int m = 0; m < 2; ++m)
#pragma unroll
          for (int n = 0; n < 4; ++n)
            acc[m][n] = __builtin_amdgcn_mfma_f32_16x16x32_bf16(
                aF[m], bF[n], acc[m][n], 0, 0, 0);
      }
    }
    __syncthreads();
  }

  // fi tile -> LDS (only active waves; inactive rows never read)
  if (wactive) {
#pragma unroll
    for (int m = 0; m < 2; ++m) {
#pragma unroll
      for (int n = 0; n < 4; ++n) {
        int hl_ = n * 16 + l15;
        float bv = bfi[colBase + hl_] + gfi[(size_t)b * H_ + colBase + hl_];
#pragma unroll
        for (int j = 0; j < 4; ++j) {
          int l = w * 32 + m * 16 + l4 * 4 + j;
          sfi[hl_ * 129 + l] = acc[m][n][j] + bv;
        }
      }
    }
  }
  __syncthreads();

  // online softmax over slots: 4 threads per column, 32 l each
  {
    int h = tid & 63, q = tid >> 6;
    int hcol = colBase + h;
    const float* mp = maskf + b * L_;
    float m = -3.0e38f, s = 0.f, tv = 0.f;
    if (len > q * 32) {
      for (int l = q * 32; l < q * 32 + 32; ++l) {
        if (mp[l] > 0.f) {
          float xv = sfi[h * 129 + l];
          float vv =
              __bfloat162float(c_new[((size_t)(b * L_ + l)) * H_ + hcol]);
          float m2 = fmaxf(m, xv);
          float sc = expf(m - m2);
          float e = expf(xv - m2);
          s = s * sc + e;
          tv = tv * sc + e * vv;
          m = m2;
        }
      }
    }
    part[q * 192 + h] = m;
    part[q * 192 + 64 + h] = s;
    part[q * 192 + 128 + h] = tv;
  }
  __syncthreads();
  if (tid < 64) {
    int hcol = colBase + tid;
    int i0 = b * H_ + hcol;
    float mm = part[tid], s0 = part[64 + tid], t0 = part[128 + tid];
#pragma unroll
    for (int k = 1; k < 4; ++k) {
      float mk = part[k * 192 + tid];
      float m2 = fmaxf(mm, mk);
      float e1 = expf(mm - m2), e2 = expf(mk - m2);
      s0 = s0 * e1 + part[k * 192 + 64 + tid] * e2;
      t0 = t0 * e1 + part[k * 192 + 128 + tid] * e2;
      mm = m2;
    }
    float f = fg[i0];
    float m2 = fmaxf(mm, f);
    float ea = expf(mm - m2), eb = expf(f - m2);
    s0 = s0 * ea + eb;
    t0 = t0 * ea + cg_old[i0] * eb;
    float cgn = t0 / s0;
    float gn = og[i0] * tanhf(cgn);
    cg_new[i0] = cgn;
    g_new[i0] = gn;
  }
}

// deterministic parallel mean over L from bf16 hpad (init only)
__global__ __launch_bounds__(256) void reduce_mean_v2(
    const bf16* __restrict__ hpad, const float* __restrict__ invlens,
    float* __restrict__ outf) {
  __shared__ float sm[4][64];
  int b = blockIdx.y, h0 = blockIdx.x * 64;
  int lg = threadIdx.x >> 6, hh = threadIdx.x & 63;
  float s = 0.f;
  for (int l = lg * 32; l < lg * 32 + 32; ++l)
    s += __bfloat162float(hpad[((size_t)(b * LP + l + 1)) * H_ + h0 + hh]);
  sm[lg][hh] = s;
  __syncthreads();
  if (threadIdx.x < 64) {
    int t = threadIdx.x;
    outf[b * H_ + h0 + t] =
        (sm[0][t] + sm[1][t] + sm[2][t] + sm[3][t]) * invlens[b];
  }
}

// ---------------- fused final head -------------------------------------------
__global__ __launch_bounds__(256) void final_head_kernel(
    const float* __restrict__ g, const float* __restrict__ W1,
    const float* __restrict__ b1, const float* __restrict__ W2,
    const float* __restrict__ b2, float* __restrict__ out) {
  __shared__ float gv[H_];
  __shared__ float t1s[2 * H_];
  __shared__ float red[256][6];
  const int b = blockIdx.x;
  const int tid = threadIdx.x;
  for (int i = tid; i < H_; i += 256) gv[i] = g[b * H_ + i];
  __syncthreads();
  float accp[4];
#pragma unroll
  for (int p = 0; p < 4; ++p) accp[p] = b1[tid + p * 256];
  for (int k = 0; k < H_; ++k) {
    float gk = gv[k];
#pragma unroll
    for (int p = 0; p < 4; ++p)
      accp[p] = fmaf(gk, W1[(size_t)k * (2 * H_) + tid + p * 256], accp[p]);
  }
#pragma unroll
  for (int p = 0; p < 4; ++p) t1s[tid + p * 256] = tanhf(accp[p]);
  __syncthreads();
  float pd[DOUT_] = {0.f, 0.f, 0.f, 0.f, 0.f};
#pragma unroll
  for (int p = 0; p < 4; ++p) {
    int j = tid + p * 256;
    float tv = t1s[j];
#pragma unroll
    for (int d = 0; d < DOUT_; ++d)
      pd[d] = fmaf(tv, W2[(size_t)j * DOUT_ + d], pd[d]);
  }
#pragma unroll
  for (int d = 0; d < DOUT_; ++d) red[tid][d] = pd[d];
  __syncthreads();
  for (int stride = 128; stride >= 1; stride >>= 1) {
    if (tid < stride) {
#pragma unroll
      for (int d = 0; d < DOUT_; ++d) red[tid][d] += red[tid + stride][d];
    }
    __syncthreads();
  }
  if (tid == 0) {
    float lg[DOUT_];
#pragma unroll
    for (int d = 0; d < DOUT_; ++d) lg[d] = red[0][d] + b2[d];
    float m = lg[0];
#pragma unroll
    for (int d = 1; d < DOUT_; ++d) m = fmaxf(m, lg[d]);
    float s = 0.f;
#pragma unroll
    for (int d = 0; d < DOUT_; ++d) s += expf(lg[d] - m);
    float ls = logf(s);
#pragma unroll
    for (int d = 0; d < DOUT_; ++d) out[b * DOUT_ + d] = lg[d] - m - ls;
  }
}

// ---------------- host ----------------
extern "C" void kernel_launch(void* const* d_in, const int* in_sizes, int n_in,
                              void* d_out, int out_size, void* d_ws,
                              size_t ws_size, hipStream_t stream) {
  (void)in_sizes; (void)n_in; (void)out_size; (void)ws_size;
  const int* tokens = (const int*)d_in[0];
  const int* lengths = (const int*)d_in[1];
  const float* embed = (const float*)d_in[2];
  const float* W0 = (const float*)d_in[3];
  const float* b0 = (const float*)d_in[4];
  const float* Wg = (const float*)d_in[5];
  const float* bg = (const float*)d_in[6];
  const float* Wgf = (const float*)d_in[7];
  const float* bgf = (const float*)d_in[8];
  const float* Wfi = (const float*)d_in[9];
  const float* bfi = (const float*)d_in[10];
  const float* Wgo = (const float*)d_in[11];
  const float* bgo = (const float*)d_in[12];
  const float* W1 = (const float*)d_in[13];
  const float* b1 = (const float*)d_in[14];
  const float* W2 = (const float*)d_in[15];
  const float* b2 = (const float*)d_in[16];
  float* out = (float*)d_out;

  float* ws = (float*)d_ws;
  size_t off = 0;
  auto alloc = [&](size_t nf) {
    float* p = ws + off;
    off += (nf + 7) & ~(size_t)7;
    return p;
  };
  bf16* xb = (bf16*)alloc((size_t)B_ * L_ * EP / 2);       // [4096][320]
  float* maskf = alloc(B_ * L_);
  float* invlens = alloc(B_);
  bf16* hpad0 = (bf16*)alloc((size_t)B_ * LP * H_ / 2);    // [32][130][512]
  bf16* hpad1 = (bf16*)alloc((size_t)B_ * LP * H_ / 2);
  bf16* cb0 = (bf16*)alloc((size_t)B_ * L_ * H_ / 2);      // bf16 c
  bf16* cb1 = (bf16*)alloc((size_t)B_ * L_ * H_ / 2);
  float* g = alloc(B_ * H_);
  float* cgb0 = alloc(B_ * H_);
  float* cgb1 = alloc(B_ * H_);
  float* havg_part = alloc((size_t)2 * B_ * H_);           // [2][32][512]
  float* fg = alloc(B_ * H_);
  float* og = alloc(B_ * H_);
  float* gg = alloc((size_t)B_ * G7);                      // [32][3584]
  float* gfi = alloc(B_ * H_);                             // [32][512]
  bf16* Wgt = (bf16*)alloc((size_t)G7 * KGATES / 2);       // [3584][1856]
  bf16* W0t = (bf16*)alloc((size_t)H_ * EP / 2);           // [512][320]
  bf16* Wfit = (bf16*)alloc((size_t)H_ * KFI / 2);         // [512][512]

  // ---- init ----
  mask_lens_kernel<<<(B_ * L_ + 255) / 256, 256, 0, stream>>>(lengths, maskf,
                                                              invlens);
  embed_bf16_kernel<<<(B_ * L_ * EP + 255) / 256, 256, 0, stream>>>(tokens,
                                                                    embed, xb);
  transpose_to_bf16<<<dim3(24, G7 / 64), 256, 0, stream>>>(Wg, Wgt, 1536, G7,
                                                           KGATES);
  transpose_to_bf16<<<dim3(5, G7 / 64), 256, 0, stream>>>(
      Wg + (size_t)1536 * G7, Wgt + 1536, 300, G7, KGATES);
  transpose_to_bf16<<<dim3(5, H_ / 64), 256, 0, stream>>>(W0, W0t, 300, H_, EP);
  transpose_to_bf16<<<dim3(8, H_ / 64), 256, 0, stream>>>(
      Wfi + (size_t)H_ * H_, Wfit, H_, H_, KFI);  // bottom 512 rows (h part)
  fill_pad2<<<(B_ * 2 * H_ + 255) / 256, 256, 0, stream>>>(hpad0, hpad1);
  // h0 = tanh(xb @ W0 + b0) * mask -> hpad0
  gemm_mfma_init<<<dim3(H_ / 128, (B_ * L_) / 128), 256, 0, stream>>>(
      xb, W0t, b0, maskf, hpad0, H_, EP);
  reduce_mean_v2<<<dim3(8, B_), 256, 0, stream>>>(hpad0, invlens, g);
  fill_zero<<<(B_ * L_ * H_ / 2 + 255) / 256, 256, 0, stream>>>(
      (float*)cb0, B_ * L_ * H_ / 2);
  fill_zero<<<(B_ * H_ + 255) / 256, 256, 0, stream>>>(cgb0, B_ * H_);
  fill_zero<<<(B_ * H_ + 255) / 256, 256, 0, stream>>>(havg_part + B_ * H_,
                                                       B_ * H_);

  bf16* cb[2] = {cb0, cb1};
  bf16* hp[2] = {hpad0, hpad1};
  float* cgb[2] = {cgb0, cgb1};
  int cur = 0;
  for (int step = 0; step < NSTEP; ++step) {
    int nxt = cur ^ 1;
    // per-batch g contributions (gg for gates, gfi for fi)
    gvec_gemm<<<dim3(64, B_), 256, 0, stream>>>(g, Wg + (size_t)1836 * G7,
                                                Wfi, gg, gfi);
    // gates GEMM + cell update + h-mean, fused (BM=128, wave-level skip)
    gates_cell_kernel<<<dim3(32, 32), 256, 0, stream>>>(
        hp[cur], xb, Wgt, bg, gg, lengths, cb[cur], cgb[cur], cb[nxt],
        hp[nxt], havg_part);
    gnode_vec<<<dim3(8, B_, 2), 256, 0, stream>>>(
        g, havg_part, invlens, Wgf, bgf, fg, Wgo, bgo, og);
    fi_slot_kernel<<<dim3(8, B_), 256, 0, stream>>>(
        hp[nxt], Wfit, bfi, gfi, fg, og, cb[nxt], cgb[cur], maskf, lengths,
        cgb[nxt], g);
    cur = nxt;
  }
  final_head_kernel<<<B_, 256, 0, stream>>>(g, W1, b1, W2, b2, out);
}